// Round 20
// baseline (684.213 us; speedup 1.0000x reference)
//
#include <hip/hip_runtime.h>
#include <hip/hip_bf16.h>
#include <stdint.h>

#define HWDIM 48
#define PLANE 2304            // 48*48
#define NB 8
#define NT 12
#define CHID 96
#define OC 384                // 4*HID
#define KTOT 1728
#define BN 144                // spatial cols per block (3 image rows)
#define NBLK_JOB 128          // 18432 / 144
#define NCHUNK 54             // 1728 / 32
#define PPLANE 2500           // 50*50 (48x48 interior + zero halo)
#define PGRP 3                // 32-ch groups per 96-ch image
#define HPS 104               // HP row stride (208B ≡ 20 dwords mod 32 -> 2-way, free)
#define IMG_E ((size_t)PGRP * PPLANE * 32)     // packed elems per image = 240000
#define SLOT_E ((size_t)NB * IMG_E)            // packed elems per slot (8 imgs)
#define BT ((size_t)CHID * PLANE)              // 221184

typedef __attribute__((ext_vector_type(8))) short short8;
typedef __attribute__((ext_vector_type(4))) float f32x4;
typedef __attribute__((ext_vector_type(4))) unsigned int u32x4;

__device__ __forceinline__ unsigned short f2bf(float f) {
  union { float f; uint32_t u; } x; x.f = f;
  uint32_t u = x.u;
  return (unsigned short)((u + 0x7FFFu + ((u >> 16) & 1u)) >> 16);  // RNE
}

// ---------------- weight repack (fragment-direct, GATE-INTERLEAVED rows) ----------------
// Permuted row space: new_row = ch*4 + gate  (ch 0..95, gate 0..3 = i,f,o,g).
__global__ void convlstm_wconv(const float* __restrict__ W, unsigned short* __restrict__ Wb, int total) {
  int idx = blockIdx.x * 256 + threadIdx.x;
  if (idx >= total) return;
  const int PER_L = NCHUNK * 24 * 64 * 8;      // 663552
  int layer = idx / PER_L;
  int r = idx - layer * PER_L;
  int jj = r & 7;
  int l = (r >> 3) & 63;
  int fr = r >> 9;                  // c*24 + rm
  int rm = fr % 24;
  int c = fr / 24;
  int oc = rm * 16 + (l & 15);                 // permuted row
  int oco = (oc & 3) * 96 + (oc >> 2);         // original row = gate*96 + ch
  int k = c * 32 + ((l >> 4) << 3) + jj;
  int tap = k / 192;
  int ic = k - tap * 192;
  float v = W[(((size_t)layer * OC + oco) * 192 + ic) * 9 + tap];
  Wb[idx] = f2bf(v);
}

// ---------------- activation packing: f32 [img][96][2304] -> bf16 [slot][3][50][50][32] interior ----------------
__global__ void pack_interior(const float* __restrict__ src, unsigned short* __restrict__ dst,
                              int mode, int t_base, int slot_mask) {
  __shared__ float T[32][65];
  int bid = blockIdx.x;
  int tile = bid % 36;
  int grp  = (bid / 36) % 3;
  int imgi = bid / 108;
  int slot; size_t srcoff;
  if (mode == 0) {                  // x: imgi = (t - t_base)*8 + b
    int b = imgi & 7; int t = t_base + (imgi >> 3);
    srcoff = ((size_t)b * NT + t) * BT;
    slot = (t & slot_mask) * NB + b;
  } else {                          // h0: imgi = l*8 + b -> ph slot (l*2+1), image b
    int b = imgi & 7; int l = imgi >> 3;
    srcoff = (size_t)imgi * BT;
    slot = (l * 2 + 1) * NB + b;
  }
  const float* s = src + srcoff + (size_t)grp * 32 * PLANE + tile * 64;
  const int tid = threadIdx.x;
#pragma unroll
  for (int r = 0; r < 8; ++r) {
    int ch = r * 4 + (tid >> 6);
    T[ch][tid & 63] = s[(size_t)ch * PLANE + (tid & 63)];
  }
  __syncthreads();
  int p = tid >> 2, sq = tid & 3;
  int pos = tile * 64 + p;
  int py = pos / 48 + 1, px = pos % 48 + 1;
  unsigned short v[8];
#pragma unroll
  for (int i = 0; i < 8; ++i) v[i] = f2bf(T[sq * 8 + i][p]);
  *(short8*)(dst + ((size_t)slot * PGRP + grp) * (PPLANE * 32) + (py * 50 + px) * 32 + sq * 8) = *(short8*)v;
}

// zero the halo border of packed planes (196 granules per [50][50][32] plane)
__global__ void border_zero(unsigned short* dst, int nplanes) {
  int idx = blockIdx.x * 256 + threadIdx.x;
  if (idx >= nplanes * 784) return;
  int plane = idx / 784;
  int r = idx - plane * 784;
  int g = r >> 2, sq = r & 3;
  int py, px;
  if (g < 50)       { py = 0;       px = g; }
  else if (g < 100) { py = 49;      px = g - 50; }
  else if (g < 148) { py = g - 99;  px = 0; }
  else              { py = g - 147; px = 49; }
  u32x4 z = {0, 0, 0, 0};
  *(u32x4*)(dst + (size_t)plane * (PPLANE * 32) + (py * 50 + px) * 32 + sq * 8) = z;
}

// ---------------- fused conv + LSTM step: 256 blocks x 8 waves, zero-exchange epilogue ----------------
struct Job {
  const unsigned short* xp;   // packed x source [8][3][2500][32] bf16
  const unsigned short* hp;   // packed h_prev source
  unsigned short* hw;         // packed h dest (parity t)
  const short8* w;            // bf16 weights fragment order [54][24][64][8], gate-interleaved rows
  const float* bias;          // [384] original layout (gate*96+ch)
  float* c_base;              // c state, b-stride 96*PLANE
  float* h_out; long long ho_bs;
  float* hf;                  // final-h slot or nullptr
};

__global__ __launch_bounds__(512, 1) void convlstm_step(Job j0, Job j1) {
  // HALO, channel-quarter-major: [gs 0..5][q 0..3][row 5][px 50] 16B granules = 96 KB.
  __shared__ __align__(16) char smem[96000];
  unsigned short* HALO = (unsigned short*)smem;
  unsigned short* HP = (unsigned short*)smem;    // epilogue alias [144 pos][HPS]

  const int tid = threadIdx.x;
  const Job j = (blockIdx.x < NBLK_JOB) ? j0 : j1;
  const int n0 = (blockIdx.x % NBLK_JOB) * BN;
  const int lane = tid & 63;
  const int wid = tid >> 6;             // 8 waves; wave owns new-rows [wid*48, wid*48+48)

  const int bb = n0 / PLANE;            // uniform per block (2304 % 144 == 0)
  const int spb = n0 - bb * PLANE;
  const int y0 = spb / 48;              // block covers image rows y0..y0+2

  // ---- one-time halo staging: 1500 position-granules (64B each), rows y0..y0+4 ----
  const unsigned short* xb = j.xp + (size_t)bb * IMG_E;
  const unsigned short* hb = j.hp + (size_t)bb * IMG_E;
  for (int it = 0; it < 3; ++it) {
    int pg = tid + it * 512;
    if (pg < 1500) {
      int tensor = pg / 750;
      int rem = pg - tensor * 750;
      int grp = rem / 250;
      int r2 = rem - grp * 250;
      int rr = r2 / 50;
      int px = r2 - rr * 50;
      int gs = tensor * 3 + grp;
      const unsigned short* src = (tensor ? hb : xb) + (size_t)grp * (PPLANE * 32)
                                  + (size_t)((y0 + rr) * 50 + px) * 32;
#pragma unroll
      for (int q = 0; q < 4; ++q) {
        short8 v = *(const short8*)(src + q * 8);
        *(short8*)&HALO[(size_t)(((gs * 4 + q) * 5 + rr) * 50 + px) * 8] = v;
      }
    }
  }

  // ---- accumulators: acc[rm][cn][r] = gate r of channel (wid*12+rm*4+(lane>>4)) ----
  f32x4 acc[3][9];
#pragma unroll
  for (int rm = 0; rm < 3; ++rm) {
    const int ch = wid * 12 + rm * 4 + (lane >> 4);
    f32x4 bi;
#pragma unroll
    for (int r = 0; r < 4; ++r) bi[r] = j.bias[r * 96 + ch];
#pragma unroll
    for (int cn = 0; cn < 9; ++cn) acc[rm][cn] = bi;
  }

  const short8* aw = j.w + (size_t)(wid * 3) * 64 + lane;    // + c*1536 + rm*64
  const int lofs = (lane >> 4) * 2000 + (lane & 15) * 8;

  auto bload = [&](int c, short8* bf) {
    const int tap = c / 6, gs2 = c - tap * 6;
    const int kh = tap / 3, kw = tap - kh * 3;
#pragma unroll
    for (int cn = 0; cn < 9; ++cn) {
      const int off = gs2 * 8000 + ((cn / 3) + kh) * 400 + ((cn % 3) * 16 + kw) * 8 + lofs;
      bf[cn] = *(const short8*)&HALO[off];
    }
  };
  auto aload = [&](int c, short8* a) {
#pragma unroll
    for (int rm = 0; rm < 3; ++rm) a[rm] = aw[(size_t)c * 1536 + rm * 64];
  };
  auto domfma = [&](short8* a, short8* b) {
    __builtin_amdgcn_s_setprio(1);
#pragma unroll
    for (int cn = 0; cn < 9; ++cn)
#pragma unroll
      for (int rm = 0; rm < 3; ++rm)
        acc[rm][cn] = __builtin_amdgcn_mfma_f32_16x16x32_bf16(a[rm], b[cn], acc[rm][cn], 0, 0, 0);
    __builtin_amdgcn_s_setprio(0);
  };

  short8 aA[3], aB[3], bA[9], bB[9];
  aload(0, aA);

  __syncthreads();   // halo resident

  bload(0, bA);

  // ---- barrier-free main loop, unrolled x2: even chunks use (aA,bA), odd use (aB,bB).
  //      No register rotation (r19's 48 v_mov/chunk deleted); prefetch 1 chunk ahead. ----
#pragma unroll 1
  for (int c = 0; c < NCHUNK; c += 2) {
    aload(c + 1, aB);            // c+1 <= 53 always (NCHUNK even)
    bload(c + 1, bB);
    domfma(aA, bA);
    if (c + 2 < NCHUNK) {
      aload(c + 2, aA);
      bload(c + 2, bA);
    }
    domfma(aB, bB);
  }

  // ---- hoist c-loads so their latency drains during the pre-epilogue barrier ----
  float cold[3][9];
#pragma unroll
  for (int rm = 0; rm < 3; ++rm) {
    const int ch = wid * 12 + rm * 4 + (lane >> 4);
    const float* cb_ = j.c_base + (size_t)bb * (CHID * PLANE) + (size_t)ch * PLANE + spb + (lane & 15);
#pragma unroll
    for (int cn = 0; cn < 9; ++cn) cold[rm][cn] = cb_[cn * 16];
  }
  __syncthreads();   // all waves done reading HALO before HP overwrites it

  // ---- zero-exchange epilogue: each lane holds (i,f,o,g) of its channel directly ----
#pragma unroll
  for (int rm = 0; rm < 3; ++rm) {
    const int ch = wid * 12 + rm * 4 + (lane >> 4);
    float* cb_ = j.c_base + (size_t)bb * (CHID * PLANE) + (size_t)ch * PLANE;
    float* hb_ = j.h_out + (size_t)bb * j.ho_bs + (size_t)ch * PLANE;
    float* hf_ = j.hf ? (j.hf + (size_t)bb * (CHID * PLANE) + (size_t)ch * PLANE) : nullptr;
#pragma unroll
    for (int cn = 0; cn < 9; ++cn) {
      const int col = cn * 16 + (lane & 15);
      const int spe = spb + col;
      const float gi = acc[rm][cn][0];
      const float gf = acc[rm][cn][1];
      const float go = acc[rm][cn][2];
      const float gg = acc[rm][cn][3];
      const float si = 1.f / (1.f + __expf(-gi));
      const float sf = 1.f / (1.f + __expf(-gf));
      const float so = 1.f / (1.f + __expf(-go));
      const float e2g = __expf(2.f * gg);
      const float tg = 1.f - 2.f / (e2g + 1.f);     // tanh(gg)
      const float cn2 = sf * cold[rm][cn] + si * tg;
      const float e2c = __expf(2.f * cn2);
      const float tc = 1.f - 2.f / (e2c + 1.f);     // tanh(cn)
      const float hn = so * tc;
      cb_[spe] = cn2;
      hb_[spe] = hn;
      if (hf_) hf_[spe] = hn;
      HP[col * HPS + ch] = f2bf(hn);
    }
  }
  __syncthreads();

  // coalesced packed-h store: 1728 16B granules = [grp*4+sq][144 pos]
#pragma unroll
  for (int it = 0; it < 4; ++it) {
    int gi = tid + it * 512;
    if (gi < 1728) {
      int gq = gi / 144;             // grp*4 + sq
      int p  = gi - gq * 144;
      int grp = gq >> 2, sq = gq & 3;
      int pos = spb + p;
      int py = pos / 48 + 1, px = pos % 48 + 1;
      short8 v = *(short8*)&HP[p * HPS + grp * 32 + sq * 8];
      *(short8*)(j.hw + (size_t)bb * IMG_E + (size_t)grp * (PPLANE * 32) + (py * 50 + px) * 32 + sq * 8) = v;
    }
  }
}

extern "C" void kernel_launch(void* const* d_in, const int* in_sizes, int n_in,
                              void* d_out, int out_size, void* d_ws, size_t ws_size,
                              hipStream_t stream) {
  const float* inp  = (const float*)d_in[0];   // [8,12,96,48,48]
  const float* h0   = (const float*)d_in[1];   // [2,8,96,48,48]
  const float* c0   = (const float*)d_in[2];   // [2,8,96,48,48]
  const float* W    = (const float*)d_in[3];   // [2,384,192,3,3]
  const float* bias = (const float*)d_in[4];   // [2,384]

  float* AH = (float*)d_out;                   // [2,8,12,96,48,48]
  float* HF = AH + (size_t)2 * NB * NT * BT;   // [2,8,96,48,48]
  float* CF = HF + (size_t)2 * NB * BT;        // [2,8,96,48,48] running c

  // workspace layout: [Wb | ph (4 slots) | px (12 or 2 slots)]
  const size_t WB_BYTES = (size_t)2 * NCHUNK * 24 * 64 * 8 * 2;          // 2,654,208
  const size_t PH_BYTES = (size_t)4 * SLOT_E * 2;                        // 15,360,000
  const size_t PX_BIG   = (size_t)NT * SLOT_E * 2;                       // 46,080,000
  const bool big = ws_size >= WB_BYTES + PH_BYTES + PX_BIG;
  unsigned short* Wb = (unsigned short*)d_ws;
  unsigned short* ph = (unsigned short*)((char*)d_ws + WB_BYTES);
  unsigned short* px = (unsigned short*)((char*)d_ws + WB_BYTES + PH_BYTES);

  // 1) repack weights (gate-interleaved rows)
  {
    int total = 2 * NCHUNK * 24 * 64 * 8;
    convlstm_wconv<<<(total + 255) / 256, 256, 0, stream>>>(W, Wb, total);
  }
  // 2) zero halo borders
  {
    int np_ph = 4 * NB * 3;
    border_zero<<<(np_ph * 784 + 255) / 256, 256, 0, stream>>>(ph, np_ph);
    int np_px = (big ? NT : 2) * NB * 3;
    border_zero<<<(np_px * 784 + 255) / 256, 256, 0, stream>>>(px, np_px);
  }
  // 3) pack x (all t if big, else t=0,1) and h0
  {
    int n_img = big ? (NT * NB) : (2 * NB);
    pack_interior<<<n_img * 108, 256, 0, stream>>>(inp, px, 0, 0, big ? 15 : 1);
    pack_interior<<<2 * NB * 108, 256, 0, stream>>>(h0, ph, 1, 0, 0);
  }
  // 4) running c state
  hipMemcpyAsync(CF, c0, (size_t)2 * NB * BT * sizeof(float), hipMemcpyDeviceToDevice, stream);

  const size_t PER_L = (size_t)NCHUNK * 24 * 64;   // short8 units per layer

  auto mkjob = [&](int l, int t) -> Job {
    Job j;
    if (l == 0) j.xp = px + (size_t)(big ? t : (t & 1)) * SLOT_E;
    else        j.xp = ph + (size_t)(0 * 2 + (t & 1)) * SLOT_E;          // layer0's packed h at t
    j.hp = ph + (size_t)(l * 2 + ((t + 1) & 1)) * SLOT_E;                // parity of t-1
    j.hw = ph + (size_t)(l * 2 + (t & 1)) * SLOT_E;
    j.w = (const short8*)Wb + (size_t)l * PER_L;
    j.bias = bias + l * OC;
    j.c_base = CF + (size_t)l * NB * BT;
    j.h_out = AH + (size_t)l * NB * NT * BT + (size_t)t * BT;
    j.ho_bs = (long long)NT * BT;
    j.hf = (t == NT - 1) ? (HF + (size_t)l * NB * BT) : nullptr;
    return j;
  };

  for (int k = 0; k <= NT; ++k) {
    const bool hasA = (k <= NT - 1);   // layer0, t=k
    const bool hasB = (k >= 1);        // layer1, t=k-1
    Job ja, jb;
    int njobs = 0;
    if (hasA) { ja = mkjob(0, k); njobs = 1; }
    if (hasB) {
      Job xj = mkjob(1, k - 1);
      if (njobs) jb = xj; else ja = xj;
      njobs++;
    }
    if (njobs == 1) jb = ja;
    convlstm_step<<<njobs * NBLK_JOB, 512, 0, stream>>>(ja, jb);
    if (!big && k + 2 <= NT - 1)
      pack_interior<<<NB * 108, 256, 0, stream>>>(inp, px, 0, k + 2, 1);
  }
}

// Round 21
// 670.247 us; speedup vs baseline: 1.0208x; 1.0208x over previous
//
#include <hip/hip_runtime.h>
#include <hip/hip_bf16.h>
#include <stdint.h>

#define HWDIM 48
#define PLANE 2304            // 48*48
#define NB 8
#define NT 12
#define CHID 96
#define OC 384                // 4*HID
#define KTOT 1728
#define BN 144                // spatial cols per block (3 image rows)
#define NBLK_JOB 128          // 18432 / 144
#define NCHUNK 54             // 1728 / 32
#define PPLANE 2500           // 50*50 (48x48 interior + zero halo)
#define PGRP 3                // 32-ch groups per 96-ch image
#define HPS 104               // HP row stride (208B ≡ 20 dwords mod 32 -> 2-way, free)
#define IMG_E ((size_t)PGRP * PPLANE * 32)     // packed elems per image = 240000
#define SLOT_E ((size_t)NB * IMG_E)            // packed elems per slot (8 imgs)
#define BT ((size_t)CHID * PLANE)              // 221184

typedef __attribute__((ext_vector_type(8))) short short8;
typedef __attribute__((ext_vector_type(4))) float f32x4;
typedef __attribute__((ext_vector_type(4))) unsigned int u32x4;

__device__ __forceinline__ unsigned short f2bf(float f) {
  union { float f; uint32_t u; } x; x.f = f;
  uint32_t u = x.u;
  return (unsigned short)((u + 0x7FFFu + ((u >> 16) & 1u)) >> 16);  // RNE
}

// ---------------- weight repack (fragment-direct, GATE-INTERLEAVED rows) ----------------
// Permuted row space: new_row = ch*4 + gate  (ch 0..95, gate 0..3 = i,f,o,g).
__global__ void convlstm_wconv(const float* __restrict__ W, unsigned short* __restrict__ Wb, int total) {
  int idx = blockIdx.x * 256 + threadIdx.x;
  if (idx >= total) return;
  const int PER_L = NCHUNK * 24 * 64 * 8;      // 663552
  int layer = idx / PER_L;
  int r = idx - layer * PER_L;
  int jj = r & 7;
  int l = (r >> 3) & 63;
  int fr = r >> 9;                  // c*24 + rm
  int rm = fr % 24;
  int c = fr / 24;
  int oc = rm * 16 + (l & 15);                 // permuted row
  int oco = (oc & 3) * 96 + (oc >> 2);         // original row = gate*96 + ch
  int k = c * 32 + ((l >> 4) << 3) + jj;
  int tap = k / 192;
  int ic = k - tap * 192;
  float v = W[(((size_t)layer * OC + oco) * 192 + ic) * 9 + tap];
  Wb[idx] = f2bf(v);
}

// ---------------- activation packing: f32 [img][96][2304] -> bf16 [slot][3][50][50][32] interior ----------------
__global__ void pack_interior(const float* __restrict__ src, unsigned short* __restrict__ dst,
                              int mode, int t_base, int slot_mask) {
  __shared__ float T[32][65];
  int bid = blockIdx.x;
  int tile = bid % 36;
  int grp  = (bid / 36) % 3;
  int imgi = bid / 108;
  int slot; size_t srcoff;
  if (mode == 0) {                  // x: imgi = (t - t_base)*8 + b
    int b = imgi & 7; int t = t_base + (imgi >> 3);
    srcoff = ((size_t)b * NT + t) * BT;
    slot = (t & slot_mask) * NB + b;
  } else {                          // h0: imgi = l*8 + b -> ph slot (l*2+1), image b
    int b = imgi & 7; int l = imgi >> 3;
    srcoff = (size_t)imgi * BT;
    slot = (l * 2 + 1) * NB + b;
  }
  const float* s = src + srcoff + (size_t)grp * 32 * PLANE + tile * 64;
  const int tid = threadIdx.x;
#pragma unroll
  for (int r = 0; r < 8; ++r) {
    int ch = r * 4 + (tid >> 6);
    T[ch][tid & 63] = s[(size_t)ch * PLANE + (tid & 63)];
  }
  __syncthreads();
  int p = tid >> 2, sq = tid & 3;
  int pos = tile * 64 + p;
  int py = pos / 48 + 1, px = pos % 48 + 1;
  unsigned short v[8];
#pragma unroll
  for (int i = 0; i < 8; ++i) v[i] = f2bf(T[sq * 8 + i][p]);
  *(short8*)(dst + ((size_t)slot * PGRP + grp) * (PPLANE * 32) + (py * 50 + px) * 32 + sq * 8) = *(short8*)v;
}

// zero the halo border of packed planes (196 granules per [50][50][32] plane)
__global__ void border_zero(unsigned short* dst, int nplanes) {
  int idx = blockIdx.x * 256 + threadIdx.x;
  if (idx >= nplanes * 784) return;
  int plane = idx / 784;
  int r = idx - plane * 784;
  int g = r >> 2, sq = r & 3;
  int py, px;
  if (g < 50)       { py = 0;       px = g; }
  else if (g < 100) { py = 49;      px = g - 50; }
  else if (g < 148) { py = g - 99;  px = 0; }
  else              { py = g - 147; px = 49; }
  u32x4 z = {0, 0, 0, 0};
  *(u32x4*)(dst + (size_t)plane * (PPLANE * 32) + (py * 50 + px) * 32 + sq * 8) = z;
}

// ---------------- fused conv + LSTM step: 256 blocks x 8 waves, zero-exchange epilogue ----------------
struct Job {
  const unsigned short* xp;   // packed x source [8][3][2500][32] bf16
  const unsigned short* hp;   // packed h_prev source
  unsigned short* hw;         // packed h dest (parity t)
  const short8* w;            // bf16 weights fragment order [54][24][64][8], gate-interleaved rows
  const float* bias;          // [384] original layout (gate*96+ch)
  float* c_base;              // c state, b-stride 96*PLANE
  float* h_out; long long ho_bs;
  float* hf;                  // final-h slot or nullptr
};

__global__ __launch_bounds__(512, 1) void convlstm_step(Job j0, Job j1) {
  // HALO, channel-quarter-major: [gs 0..5][q 0..3][row 5][px 50] 16B granules = 96 KB.
  __shared__ __align__(16) char smem[96000];
  unsigned short* HALO = (unsigned short*)smem;
  unsigned short* HP = (unsigned short*)smem;    // epilogue alias [144 pos][HPS]

  const int tid = threadIdx.x;
  const Job j = (blockIdx.x < NBLK_JOB) ? j0 : j1;
  const int n0 = (blockIdx.x % NBLK_JOB) * BN;
  const int lane = tid & 63;
  const int wid = tid >> 6;             // 8 waves; wave owns new-rows [wid*48, wid*48+48)

  const int bb = n0 / PLANE;            // uniform per block (2304 % 144 == 0)
  const int spb = n0 - bb * PLANE;
  const int y0 = spb / 48;              // block covers image rows y0..y0+2

  // ---- one-time halo staging: 1500 position-granules (64B each), rows y0..y0+4 ----
  const unsigned short* xb = j.xp + (size_t)bb * IMG_E;
  const unsigned short* hb = j.hp + (size_t)bb * IMG_E;
  for (int it = 0; it < 3; ++it) {
    int pg = tid + it * 512;
    if (pg < 1500) {
      int tensor = pg / 750;
      int rem = pg - tensor * 750;
      int grp = rem / 250;
      int r2 = rem - grp * 250;
      int rr = r2 / 50;
      int px = r2 - rr * 50;
      int gs = tensor * 3 + grp;
      const unsigned short* src = (tensor ? hb : xb) + (size_t)grp * (PPLANE * 32)
                                  + (size_t)((y0 + rr) * 50 + px) * 32;
#pragma unroll
      for (int q = 0; q < 4; ++q) {
        short8 v = *(const short8*)(src + q * 8);
        *(short8*)&HALO[(size_t)(((gs * 4 + q) * 5 + rr) * 50 + px) * 8] = v;
      }
    }
  }

  // ---- accumulators: acc[rm][cn][r] = gate r of channel (wid*12+rm*4+(lane>>4)) ----
  f32x4 acc[3][9];
#pragma unroll
  for (int rm = 0; rm < 3; ++rm) {
    const int ch = wid * 12 + rm * 4 + (lane >> 4);
    f32x4 bi;
#pragma unroll
    for (int r = 0; r < 4; ++r) bi[r] = j.bias[r * 96 + ch];
#pragma unroll
    for (int cn = 0; cn < 9; ++cn) acc[rm][cn] = bi;
  }

  const short8* aw = j.w + (size_t)(wid * 3) * 64 + lane;    // + c*1536 + rm*64
  short8 a_cur[3];
#pragma unroll
  for (int rm = 0; rm < 3; ++rm) a_cur[rm] = aw[rm * 64];

  __syncthreads();   // halo resident

  // ---- co-SIMD wave desync: waves wid and wid+4 share a SIMD and run identical code in
  //      lockstep (load-burst / MFMA-burst aligned -> matrix pipe idles ~40%). Delay odd
  //      waves ~800 cyc so the two waves' phases interleave; the barrier-free K-loop
  //      never resyncs them. Wave-uniform branch (scalar), dead cost for even waves. ----
  if (wid & 1) {
    float xD = 1.0f;
#pragma unroll
    for (int i = 0; i < 200; ++i) xD = __builtin_fmaf(xD, 0.9999f, 0.0001f);
    asm volatile("" :: "v"(xD));   // keep the chain live (rule #17)
  }

  // per-lane constant part of B ds_read address (elems): q-plane (2000 elems) + px
  const int lofs = (lane >> 4) * 2000 + (lane & 15) * 8;

  auto bload = [&](int c, short8* bf) {
    const int tap = c / 6, gs2 = c - tap * 6;
    const int kh = tap / 3, kw = tap - kh * 3;
#pragma unroll
    for (int cn = 0; cn < 9; ++cn) {
      const int off = gs2 * 8000 + ((cn / 3) + kh) * 400 + ((cn % 3) * 16 + kw) * 8 + lofs;
      bf[cn] = *(const short8*)&HALO[off];
    }
  };

  short8 b_cur[9];
  bload(0, b_cur);

  // ---- barrier-free main loop: A(global)+B(LDS) prefetch 1 ahead, 27 MFMA/wave/chunk ----
#pragma unroll 1
  for (int c = 0; c < NCHUNK; ++c) {
    const int c1 = (c + 1 < NCHUNK) ? (c + 1) : (NCHUNK - 1);   // clamped (harmless re-load)
    short8 a_nxt[3];
#pragma unroll
    for (int rm = 0; rm < 3; ++rm) a_nxt[rm] = aw[(size_t)c1 * 1536 + rm * 64];
    short8 b_nxt[9];
    bload(c1, b_nxt);

    __builtin_amdgcn_s_setprio(1);
#pragma unroll
    for (int cn = 0; cn < 9; ++cn)
#pragma unroll
      for (int rm = 0; rm < 3; ++rm)
        acc[rm][cn] = __builtin_amdgcn_mfma_f32_16x16x32_bf16(a_cur[rm], b_cur[cn], acc[rm][cn], 0, 0, 0);
    __builtin_amdgcn_s_setprio(0);

#pragma unroll
    for (int rm = 0; rm < 3; ++rm) a_cur[rm] = a_nxt[rm];
#pragma unroll
    for (int cn = 0; cn < 9; ++cn) b_cur[cn] = b_nxt[cn];
  }

  // ---- hoist c-loads so their latency drains during the pre-epilogue barrier ----
  float cold[3][9];
#pragma unroll
  for (int rm = 0; rm < 3; ++rm) {
    const int ch = wid * 12 + rm * 4 + (lane >> 4);
    const float* cb_ = j.c_base + (size_t)bb * (CHID * PLANE) + (size_t)ch * PLANE + spb + (lane & 15);
#pragma unroll
    for (int cn = 0; cn < 9; ++cn) cold[rm][cn] = cb_[cn * 16];
  }
  __syncthreads();   // all waves done reading HALO before HP overwrites it

  // ---- zero-exchange epilogue: each lane holds (i,f,o,g) of its channel directly ----
#pragma unroll
  for (int rm = 0; rm < 3; ++rm) {
    const int ch = wid * 12 + rm * 4 + (lane >> 4);
    float* cb_ = j.c_base + (size_t)bb * (CHID * PLANE) + (size_t)ch * PLANE;
    float* hb_ = j.h_out + (size_t)bb * j.ho_bs + (size_t)ch * PLANE;
    float* hf_ = j.hf ? (j.hf + (size_t)bb * (CHID * PLANE) + (size_t)ch * PLANE) : nullptr;
#pragma unroll
    for (int cn = 0; cn < 9; ++cn) {
      const int col = cn * 16 + (lane & 15);
      const int spe = spb + col;
      const float gi = acc[rm][cn][0];
      const float gf = acc[rm][cn][1];
      const float go = acc[rm][cn][2];
      const float gg = acc[rm][cn][3];
      const float si = 1.f / (1.f + __expf(-gi));
      const float sf = 1.f / (1.f + __expf(-gf));
      const float so = 1.f / (1.f + __expf(-go));
      const float e2g = __expf(2.f * gg);
      const float tg = 1.f - 2.f / (e2g + 1.f);     // tanh(gg)
      const float cn2 = sf * cold[rm][cn] + si * tg;
      const float e2c = __expf(2.f * cn2);
      const float tc = 1.f - 2.f / (e2c + 1.f);     // tanh(cn)
      const float hn = so * tc;
      cb_[spe] = cn2;
      hb_[spe] = hn;
      if (hf_) hf_[spe] = hn;
      HP[col * HPS + ch] = f2bf(hn);
    }
  }
  __syncthreads();

  // coalesced packed-h store: 1728 16B granules = [grp*4+sq][144 pos]
#pragma unroll
  for (int it = 0; it < 4; ++it) {
    int gi = tid + it * 512;
    if (gi < 1728) {
      int gq = gi / 144;             // grp*4 + sq
      int p  = gi - gq * 144;
      int grp = gq >> 2, sq = gq & 3;
      int pos = spb + p;
      int py = pos / 48 + 1, px = pos % 48 + 1;
      short8 v = *(short8*)&HP[p * HPS + grp * 32 + sq * 8];
      *(short8*)(j.hw + (size_t)bb * IMG_E + (size_t)grp * (PPLANE * 32) + (py * 50 + px) * 32 + sq * 8) = v;
    }
  }
}

extern "C" void kernel_launch(void* const* d_in, const int* in_sizes, int n_in,
                              void* d_out, int out_size, void* d_ws, size_t ws_size,
                              hipStream_t stream) {
  const float* inp  = (const float*)d_in[0];   // [8,12,96,48,48]
  const float* h0   = (const float*)d_in[1];   // [2,8,96,48,48]
  const float* c0   = (const float*)d_in[2];   // [2,8,96,48,48]
  const float* W    = (const float*)d_in[3];   // [2,384,192,3,3]
  const float* bias = (const float*)d_in[4];   // [2,384]

  float* AH = (float*)d_out;                   // [2,8,12,96,48,48]
  float* HF = AH + (size_t)2 * NB * NT * BT;   // [2,8,96,48,48]
  float* CF = HF + (size_t)2 * NB * BT;        // [2,8,96,48,48] running c

  // workspace layout: [Wb | ph (4 slots) | px (12 or 2 slots)]
  const size_t WB_BYTES = (size_t)2 * NCHUNK * 24 * 64 * 8 * 2;          // 2,654,208
  const size_t PH_BYTES = (size_t)4 * SLOT_E * 2;                        // 15,360,000
  const size_t PX_BIG   = (size_t)NT * SLOT_E * 2;                       // 46,080,000
  const bool big = ws_size >= WB_BYTES + PH_BYTES + PX_BIG;
  unsigned short* Wb = (unsigned short*)d_ws;
  unsigned short* ph = (unsigned short*)((char*)d_ws + WB_BYTES);
  unsigned short* px = (unsigned short*)((char*)d_ws + WB_BYTES + PH_BYTES);

  // 1) repack weights (gate-interleaved rows)
  {
    int total = 2 * NCHUNK * 24 * 64 * 8;
    convlstm_wconv<<<(total + 255) / 256, 256, 0, stream>>>(W, Wb, total);
  }
  // 2) zero halo borders
  {
    int np_ph = 4 * NB * 3;
    border_zero<<<(np_ph * 784 + 255) / 256, 256, 0, stream>>>(ph, np_ph);
    int np_px = (big ? NT : 2) * NB * 3;
    border_zero<<<(np_px * 784 + 255) / 256, 256, 0, stream>>>(px, np_px);
  }
  // 3) pack x (all t if big, else t=0,1) and h0
  {
    int n_img = big ? (NT * NB) : (2 * NB);
    pack_interior<<<n_img * 108, 256, 0, stream>>>(inp, px, 0, 0, big ? 15 : 1);
    pack_interior<<<2 * NB * 108, 256, 0, stream>>>(h0, ph, 1, 0, 0);
  }
  // 4) running c state
  hipMemcpyAsync(CF, c0, (size_t)2 * NB * BT * sizeof(float), hipMemcpyDeviceToDevice, stream);

  const size_t PER_L = (size_t)NCHUNK * 24 * 64;   // short8 units per layer

  auto mkjob = [&](int l, int t) -> Job {
    Job j;
    if (l == 0) j.xp = px + (size_t)(big ? t : (t & 1)) * SLOT_E;
    else        j.xp = ph + (size_t)(0 * 2 + (t & 1)) * SLOT_E;          // layer0's packed h at t
    j.hp = ph + (size_t)(l * 2 + ((t + 1) & 1)) * SLOT_E;                // parity of t-1
    j.hw = ph + (size_t)(l * 2 + (t & 1)) * SLOT_E;
    j.w = (const short8*)Wb + (size_t)l * PER_L;
    j.bias = bias + l * OC;
    j.c_base = CF + (size_t)l * NB * BT;
    j.h_out = AH + (size_t)l * NB * NT * BT + (size_t)t * BT;
    j.ho_bs = (long long)NT * BT;
    j.hf = (t == NT - 1) ? (HF + (size_t)l * NB * BT) : nullptr;
    return j;
  };

  for (int k = 0; k <= NT; ++k) {
    const bool hasA = (k <= NT - 1);   // layer0, t=k
    const bool hasB = (k >= 1);        // layer1, t=k-1
    Job ja, jb;
    int njobs = 0;
    if (hasA) { ja = mkjob(0, k); njobs = 1; }
    if (hasB) {
      Job xj = mkjob(1, k - 1);
      if (njobs) jb = xj; else ja = xj;
      njobs++;
    }
    if (njobs == 1) jb = ja;
    convlstm_step<<<njobs * NBLK_JOB, 512, 0, stream>>>(ja, jb);
    if (!big && k + 2 <= NT - 1)
      pack_interior<<<NB * 108, 256, 0, stream>>>(inp, px, 0, k + 2, 1);
  }
}